// Round 1
// baseline (217.984 us; speedup 1.0000x reference)
//
#include <hip/hip_runtime.h>
#include <math.h>

typedef __attribute__((ext_vector_type(8))) short short8;
typedef __attribute__((ext_vector_type(4))) float floatx4;

#define HPAD 264  // bf16 elements per LDS h-row: 256 + 8 pad (row stride 528 B, 16B aligned)

__device__ __forceinline__ unsigned short f2bf(float x) {
    union { float f; unsigned int u; } v; v.f = x;
    unsigned int u = v.u;
    return (unsigned short)((u + 0x7fffu + ((u >> 16) & 1u)) >> 16);  // RNE
}

// ---------------------------------------------------------------------------
// Prep kernel: blocks [0,256) compute F1 = feat @ W1[4:,:]  (no bias)
//              blocks [256,288) pack W2 (fp32 row-major 256x256) into bf16
//              MFMA B-fragment order: pk[(kt*16+nt)*64 + lane][e] =
//              bf16(W2[(kt*32 + (lane>>4)*8 + e)*256 + nt*16 + (lane&15)])
// ---------------------------------------------------------------------------
__global__ __launch_bounds__(256) void prep_kernel(
    const float* __restrict__ feat,   // [32,64,256]
    const float* __restrict__ W1,     // [260,256]
    const float* __restrict__ W2,     // [256,256]
    float* __restrict__ F1,           // ws: [2048,256]
    unsigned short* __restrict__ pk)  // ws: [65536] bf16
{
    int tid = threadIdx.x;
    if (blockIdx.x < 256) {
        __shared__ float sh[8][256];
        int b  = blockIdx.x >> 3;
        int r0 = (blockIdx.x & 7) * 8;
        const float* fb = feat + (size_t)(b * 64 + r0) * 256;
        #pragma unroll
        for (int r = 0; r < 8; r++) sh[r][tid] = fb[r * 256 + tid];
        __syncthreads();
        float acc[8] = {0.f, 0.f, 0.f, 0.f, 0.f, 0.f, 0.f, 0.f};
        const float* w = W1 + 4 * 256 + tid;
        #pragma unroll 4
        for (int c = 0; c < 256; c++) {
            float wv = w[(size_t)c * 256];
            #pragma unroll
            for (int r = 0; r < 8; r++) acc[r] += sh[r][c] * wv;
        }
        float* o = F1 + (size_t)(b * 64 + r0) * 256 + tid;
        #pragma unroll
        for (int r = 0; r < 8; r++) o[r * 256] = acc[r];
    } else {
        int g = (blockIdx.x - 256) * 256 + tid;   // 0..8191
        int kt   = g >> 10;
        int rem  = g & 1023;
        int nt   = rem >> 6;
        int lane = rem & 63;
        int n  = nt * 16 + (lane & 15);
        int kb = kt * 32 + (lane >> 4) * 8;
        short8 v;
        #pragma unroll
        for (int e = 0; e < 8; e++) v[e] = (short)f2bf(W2[(size_t)(kb + e) * 256 + n]);
        ((short8*)pk)[g] = v;
    }
}

// ---------------------------------------------------------------------------
// Main kernel: one block per (b, i). 256 threads = 4 waves.
// Phase 1: geo[j] (64 entries) -> LDS
// Phase 2: h[j][d] = gelu(F1[i,d]-F1[j,d] + geo.W1geo + b1[d]) -> bf16 LDS
// Phase 3: out[b,i,j,:] = h[64x256] @ W2[256x256] + b2, via 16x16x32 bf16 MFMA
// ---------------------------------------------------------------------------
__global__ __launch_bounds__(256) void edge_kernel(
    const float* __restrict__ F1,     // [2048,256]
    const float* __restrict__ pos,    // [32,64,2]
    const float* __restrict__ W1,     // [260,256] (rows 0..3 = geo)
    const float* __restrict__ b1,     // [256]
    const unsigned short* __restrict__ pkW2, // packed bf16 W2
    const float* __restrict__ b2,     // [256]
    float* __restrict__ out)          // [32,64,64,256]
{
    __shared__ unsigned short hsh[64 * HPAD];  // 33792 B
    __shared__ float geo[64][4];               // 1024 B

    int bx  = blockIdx.x;
    int b   = bx >> 6;
    int i   = bx & 63;
    int tid = threadIdx.x;

    // ---- phase 1: geometry per j ----
    if (tid < 64) {
        float xi = pos[(b * 64 + i)   * 2 + 0], yi = pos[(b * 64 + i)   * 2 + 1];
        float xj = pos[(b * 64 + tid) * 2 + 0], yj = pos[(b * 64 + tid) * 2 + 1];
        float dx = xi - xj, dy = yi - yj;
        float dist = sqrtf(dx * dx + dy * dy);
        float ang  = atan2f(dy, dx);
        geo[tid][0] = dx; geo[tid][1] = dy; geo[tid][2] = dist; geo[tid][3] = ang;
    }
    __syncthreads();

    // ---- phase 2: h tile (each thread: 2 consecutive d, 32 j values) ----
    {
        int halfd = tid & 127;        // d pair index
        int jpar  = tid >> 7;         // j parity
        const float2* F1b2 = (const float2*)(F1 + (size_t)b * 64 * 256);
        float2 fi = F1b2[i * 128 + halfd];
        float2 w0 = ((const float2*)(W1 + 0 * 256))[halfd];
        float2 w1 = ((const float2*)(W1 + 1 * 256))[halfd];
        float2 w2 = ((const float2*)(W1 + 2 * 256))[halfd];
        float2 w3 = ((const float2*)(W1 + 3 * 256))[halfd];
        float2 bb = ((const float2*)b1)[halfd];
        int d0 = halfd * 2;
        #pragma unroll 4
        for (int jj = 0; jj < 32; jj++) {
            int j = jj * 2 + jpar;
            float4 g = *(float4*)&geo[j][0];
            float2 fj = F1b2[j * 128 + halfd];
            float x0 = fi.x - fj.x + g.x * w0.x + g.y * w1.x + g.z * w2.x + g.w * w3.x + bb.x;
            float x1 = fi.y - fj.y + g.x * w0.y + g.y * w1.y + g.z * w2.y + g.w * w3.y + bb.y;
            // exact GELU (erf form, matches approximate=False)
            float g0 = 0.5f * x0 * (1.0f + erff(x0 * 0.70710678118654752f));
            float g1 = 0.5f * x1 * (1.0f + erff(x1 * 0.70710678118654752f));
            unsigned int pv = (unsigned int)f2bf(g0) | ((unsigned int)f2bf(g1) << 16);
            *(unsigned int*)&hsh[j * HPAD + d0] = pv;
        }
    }
    __syncthreads();

    // ---- phase 3: GEMM h[64x256] @ W2[256x256] ----
    int w    = tid >> 6;          // wave id: owns cols [w*64, w*64+64)
    int lane = tid & 63;
    int q    = lane >> 4;
    int m16  = lane & 15;

    floatx4 acc[4][4];
    #pragma unroll
    for (int a = 0; a < 4; a++)
        #pragma unroll
        for (int c = 0; c < 4; c++) acc[a][c] = (floatx4){0.f, 0.f, 0.f, 0.f};

    const short8* pk = (const short8*)pkW2;
    #pragma unroll
    for (int ks = 0; ks < 8; ks++) {
        short8 afr[4];
        #pragma unroll
        for (int mt = 0; mt < 4; mt++) {
            int row = mt * 16 + m16;
            afr[mt] = *(const short8*)&hsh[row * HPAD + ks * 32 + q * 8];
        }
        short8 bfr[4];
        #pragma unroll
        for (int nt = 0; nt < 4; nt++)
            bfr[nt] = pk[(ks * 16 + (w * 4 + nt)) * 64 + lane];
        #pragma unroll
        for (int mt = 0; mt < 4; mt++)
            #pragma unroll
            for (int nt = 0; nt < 4; nt++)
                acc[mt][nt] = __builtin_amdgcn_mfma_f32_16x16x32_bf16(
                    afr[mt], bfr[nt], acc[mt][nt], 0, 0, 0);
    }

    // ---- epilogue: D[row=(q*4+r)+mt*16][col=m16+nt*16+w*64] + b2 ----
    float* ob = out + (size_t)bx * 64 * 256;
    #pragma unroll
    for (int nt = 0; nt < 4; nt++) {
        int col = w * 64 + nt * 16 + m16;
        float bias = b2[col];
        #pragma unroll
        for (int mt = 0; mt < 4; mt++) {
            int rbase = mt * 16 + q * 4;
            #pragma unroll
            for (int r = 0; r < 4; r++)
                ob[(size_t)(rbase + r) * 256 + col] = acc[mt][nt][r] + bias;
        }
    }
}

extern "C" void kernel_launch(void* const* d_in, const int* in_sizes, int n_in,
                              void* d_out, int out_size, void* d_ws, size_t ws_size,
                              hipStream_t stream) {
    const float* feat = (const float*)d_in[0];  // [32,64,256]
    const float* pos  = (const float*)d_in[1];  // [32,64,2]
    const float* W1   = (const float*)d_in[2];  // [260,256]
    const float* b1   = (const float*)d_in[3];  // [256]
    const float* W2   = (const float*)d_in[4];  // [256,256]
    const float* b2   = (const float*)d_in[5];  // [256]
    float* out = (float*)d_out;

    float* F1 = (float*)d_ws;                          // 2048*256*4 = 2 MiB
    unsigned short* pk = (unsigned short*)((char*)d_ws + 2048 * 256 * 4); // 128 KiB

    prep_kernel<<<288, 256, 0, stream>>>(feat, W1, W2, F1, pk);
    edge_kernel<<<2048, 256, 0, stream>>>(F1, pos, W1, b1, pk, b2, out);
}